// Round 5
// baseline (46.425 us; speedup 1.0000x reference)
//
#include <hip/hip_runtime.h>

// Embedding row gather: out[r, :] = data[idx[r], :]
//   idx  : 65536 x int32   (values in [0, 100000))
//   data : [100000, 512] fp32  (204.8 MB)
//   out  : [65536, 512] fp32   (134 MB, write-once)
//
// One thread per float4 of output; 128 consecutive threads share one index.
// R3/R4 falsified the cache-policy theories (nt / sc0+sc1+nt stores: all
// within noise of 44-45 us). This round targets the latency residual:
// 4x manual unroll with BATCHED independent loads (4 idx loads, then 4 row
// loads, then 4 stores) -> 4x MLP per wave. The R4 asm store's "memory"
// clobber had been blocking this reordering.

typedef float f32x4 __attribute__((ext_vector_type(4)));

#define VEC_PER_ROW 128  // 512 floats / 4

__global__ __launch_bounds__(256) void gather_rows_kernel(
        const int* __restrict__ idx,
        const f32x4* __restrict__ data,
        f32x4* __restrict__ out,
        long long total_vec4) {
    long long i = (long long)blockIdx.x * blockDim.x + threadIdx.x;
    const long long stride = (long long)gridDim.x * blockDim.x;

    // main loop: 4-way unrolled, loads batched for memory-level parallelism
    for (; i + 3 * stride < total_vec4; i += 4 * stride) {
        const long long i0 = i, i1 = i + stride, i2 = i + 2 * stride,
                        i3 = i + 3 * stride;
        const int s0 = idx[i0 >> 7];
        const int s1 = idx[i1 >> 7];
        const int s2 = idx[i2 >> 7];
        const int s3 = idx[i3 >> 7];
        const f32x4 v0 = data[(long long)s0 * VEC_PER_ROW + (i0 & 127)];
        const f32x4 v1 = data[(long long)s1 * VEC_PER_ROW + (i1 & 127)];
        const f32x4 v2 = data[(long long)s2 * VEC_PER_ROW + (i2 & 127)];
        const f32x4 v3 = data[(long long)s3 * VEC_PER_ROW + (i3 & 127)];
        __builtin_nontemporal_store(v0, &out[i0]);
        __builtin_nontemporal_store(v1, &out[i1]);
        __builtin_nontemporal_store(v2, &out[i2]);
        __builtin_nontemporal_store(v3, &out[i3]);
    }
    // tail
    for (; i < total_vec4; i += stride) {
        const int src = idx[i >> 7];
        const f32x4 v = data[(long long)src * VEC_PER_ROW + (i & 127)];
        __builtin_nontemporal_store(v, &out[i]);
    }
}

extern "C" void kernel_launch(void* const* d_in, const int* in_sizes, int n_in,
                              void* d_out, int out_size, void* d_ws, size_t ws_size,
                              hipStream_t stream) {
    const int*   idx  = (const int*)d_in[0];      // x flattened: 16384*4*1 int32
    const f32x4* data = (const f32x4*)d_in[1];    // [100000, 512] fp32
    f32x4*       out  = (f32x4*)d_out;            // [65536, 512] fp32

    const long long n_rows     = in_sizes[0];               // 65536
    const long long total_vec4 = n_rows * VEC_PER_ROW;      // 8,388,608

    // 2048 blocks x 256 = 8 blocks/CU x 4 waves = 32 waves/CU (full residency)
    // -> exactly 16 grid-stride iterations per thread = 4 unrolled batches
    const int  block  = 256;
    long long  nblk   = (total_vec4 + block - 1) / block;
    const int  grid   = (int)(nblk > 2048 ? 2048 : nblk);

    gather_rows_kernel<<<grid, block, 0, stream>>>(idx, data, out, total_vec4);
}

// Round 6
// 44.347 us; speedup vs baseline: 1.0469x; 1.0469x over previous
//
#include <hip/hip_runtime.h>

// Embedding row gather: out[r, :] = data[idx[r], :]
//   idx  : 65536 x int32   (values in [0, 100000))
//   data : [100000, 512] fp32  (204.8 MB)
//   out  : [65536, 512] fp32   (134 MB, write-once)
//
// FINAL (reverted to R3 best variant). One thread per float4 of output;
// 128 consecutive threads share one index (broadcast load); row reads and
// output writes fully coalesced (1 KB/wave/instr).
//
// Ablation history (MI355X, graph-replay timing):
//   R1 plain store .............. 45.4 us
//   R3 __builtin_nontemporal .... 44.5 us   <- best (noise-tied w/ R4)
//   R4 asm sc0 sc1 nt store ..... 44.2 us   (cache-policy: null effect)
//   R5 4x unroll batched loads .. 46.4 us   (MLP: not the bottleneck)
// No-dedup traffic = 268.6 MB -> 42.7 us floor @ 6.29 TB/s copy ceiling;
// 44.2-44.5 us = ~97% of that -> memory roofline.

typedef float f32x4 __attribute__((ext_vector_type(4)));

#define VEC_PER_ROW 128  // 512 floats / 4

__global__ __launch_bounds__(256) void gather_rows_kernel(
        const int* __restrict__ idx,
        const f32x4* __restrict__ data,
        f32x4* __restrict__ out,
        long long total_vec4) {
    long long i = (long long)blockIdx.x * blockDim.x + threadIdx.x;
    const long long stride = (long long)gridDim.x * blockDim.x;
    for (; i < total_vec4; i += stride) {
        const int row = (int)(i >> 7);        // i / VEC_PER_ROW
        const int col = (int)(i & (VEC_PER_ROW - 1));
        const int src = idx[row];
        const f32x4 v = data[(long long)src * VEC_PER_ROW + col];
        __builtin_nontemporal_store(v, &out[i]);
    }
}

extern "C" void kernel_launch(void* const* d_in, const int* in_sizes, int n_in,
                              void* d_out, int out_size, void* d_ws, size_t ws_size,
                              hipStream_t stream) {
    const int*   idx  = (const int*)d_in[0];      // x flattened: 16384*4*1 int32
    const f32x4* data = (const f32x4*)d_in[1];    // [100000, 512] fp32
    f32x4*       out  = (f32x4*)d_out;            // [65536, 512] fp32

    const long long n_rows     = in_sizes[0];               // 65536
    const long long total_vec4 = n_rows * VEC_PER_ROW;      // 8,388,608

    // 2048 blocks x 256 = 8 blocks/CU x 4 waves = 32 waves/CU (full residency)
    const int  block  = 256;
    long long  nblk   = (total_vec4 + block - 1) / block;
    const int  grid   = (int)(nblk > 2048 ? 2048 : nblk);

    gather_rows_kernel<<<grid, block, 0, stream>>>(idx, data, out, total_vec4);
}